// Round 5
// baseline (3403.864 us; speedup 1.0000x reference)
//
#include <hip/hip_runtime.h>
#include <hip/hip_bf16.h>

#define NSTEPS 64

typedef __attribute__((ext_vector_type(8))) short bf16x8;
typedef __attribute__((ext_vector_type(4))) float f32x4;

static __device__ __forceinline__ unsigned short f2bf(float v) {
  union { __hip_bfloat16 h; unsigned short u; } cv;
  cv.h = __float2bfloat16(v);
  return cv.u;
}

static __device__ __forceinline__ unsigned int cvtpk_bf16(float lo, float hi) {
  unsigned int d;
  asm("v_cvt_pk_bf16_f32 %0, %1, %2" : "=v"(d) : "v"(lo), "v"(hi));
  return d;
}

// ---------------------------------------------------------------------------
// prep (UNCHANGED, verified rounds 1/2/4): MFMA A-fragments for W1/W2 in bf16.
//
// A1 frags: [mb=8][kc=5][lane=64][j=8] bf16.  A1[m][k] with PERMUTED co:
//   co(mb, m) = (mb>>1)*32 + (m>>2)*8 + (mb&1)*4 + (m&3),  m = lane&15,
//   k = 32*kc + 8*(lane>>4) + j,  k = tap*16 + ci (9 taps), zero for k>=144.
// Permutation property: GEMM1's C/D accumulator of mb pair {2q,2q+1} IS the
// lane-exact B-fragment content for GEMM2 chunk kc2 = mb>>1 (k2 natural).
// W2 frags at element 20480: [kc2=4][lane=64][j=8], natural k2 order.
// ---------------------------------------------------------------------------
__global__ void ca_prep(const float* __restrict__ w1, const float* __restrict__ w2,
                        __hip_bfloat16* __restrict__ fr) {
  int i = blockIdx.x * 256 + threadIdx.x;
  if (i < 20480) {
    int j  = i & 7;
    int l  = (i >> 3) & 63;
    int fi = i >> 9;          // mb*5 + kc
    int kc = fi % 5, mb = fi / 5;
    int m  = l & 15;
    int co = ((mb >> 1) << 5) + ((m >> 2) << 3) + ((mb & 1) << 2) + (m & 3);
    int k  = kc * 32 + ((l >> 4) << 3) + j;
    float v = 0.0f;
    if (k < 144) {
      int tap = k >> 4, ci = k & 15;
      v = w1[(co * 16 + ci) * 9 + tap];   // w1[co][ci][dy][dx], tap=dy*3+dx
    }
    fr[i] = __float2bfloat16(v);
  } else if (i < 22528) {
    int i2  = i - 20480;
    int j   = i2 & 7;
    int l   = (i2 >> 3) & 63;
    int kc2 = i2 >> 9;
    int k2  = kc2 * 32 + ((l >> 4) << 3) + j;
    fr[i] = __float2bfloat16(w2[(l & 15) * 128 + k2]);
  }
}

// ---------------------------------------------------------------------------
// one CA step, co-sliced waves.  grid = 2048 blocks: b = bid&7 (batch->XCD),
// 16x16 grid of 16x16-px tiles.  block = 128 threads = 2 waves.
//
// Wave w owns co slice [64w, 64w+64) = mb {4w..4w+3}: its 20 A1 fragments
// (80 VGPR) + 4 W2 fragments (16 VGPR) stay RESIDENT in registers -> zero
// weight re-reads.  Per pb-pair j: phase A = each wave GEMM1 for both pbs of
// its co slice, stage relu(p) as ready-made B-fragments (kc2 = 2w+q) via one
// ds_write_b128 each; one __syncthreads; phase B = wave w does GEMM2 +
// epilogue for pb = 2j+w.  Staging double-buffered by j&1 -> 8 syncs/step.
//
// LDS (26752 B, ~6 blocks/CU):
//   [    0, 16384)  relu(p) staging [buf=2][pb&1][kc2=4][lane=64]x16B
//   [16384, 21568)  h tile ci 0..7,  [y=18][x=18] x 16B/pixel
//   [21568, 26752)  h tile ci 8..15, same
// ---------------------------------------------------------------------------
#define TILE0 16384
#define TILE1 21568

__launch_bounds__(128, 3)
__global__ void ca_step(const float* __restrict__ hin,
                        float* __restrict__ hout,
                        const __hip_bfloat16* __restrict__ fr) {
  __shared__ __align__(16) char smem[26752];
  const int tid  = threadIdx.x;
  const int lane = tid & 63;
  const int w    = tid >> 6;          // 0..1
  const int bid  = blockIdx.x;
  const int b    = bid & 7;           // batch -> XCD round-robin
  const int t    = bid >> 3;          // 0..255
  const int ty   = t >> 4;            // 0..15
  const int tx   = t & 15;            // 0..15
  const int Y0   = ty << 4, X0 = tx << 4;
  const int ib   = b << 20;           // b * 16 * 65536

  // ---- resident weights: wave w's A1 slice (mb 4w..4w+3) + full W2 ----
  bf16x8 a1[4][5];
#pragma unroll
  for (int ml = 0; ml < 4; ++ml)
#pragma unroll
    for (int kc = 0; kc < 5; ++kc) {
      const int mb = (w << 2) + ml;
      a1[ml][kc] = *(const bf16x8*)(fr + (((mb * 5 + kc) * 64 + lane) << 3));
    }
  bf16x8 w2f[4];
#pragma unroll
  for (int kc = 0; kc < 4; ++kc)
    w2f[kc] = *(const bf16x8*)(fr + 20480 + ((kc * 64 + lane) << 3));
#pragma unroll
  for (int ml = 0; ml < 4; ++ml)
#pragma unroll
    for (int kc = 0; kc < 5; ++kc)
      asm volatile("" : "+v"(a1[ml][kc]));
#pragma unroll
  for (int kc = 0; kc < 4; ++kc)
    asm volatile("" : "+v"(w2f[kc]));

  // ---- halo'd tile load: 18x18 px x 16 ch, f32 -> bf16 ----
  for (int i = tid; i < 18 * 18; i += 128) {
    int y  = i / 18;
    int x  = i - y * 18;
    int GY = Y0 + y - 1, GX = X0 + x - 1;
    bool inb = ((unsigned)GY < 256u) && ((unsigned)GX < 256u);
    int gof = ib + (GY << 8) + GX;
    unsigned int pk[8];
#pragma unroll
    for (int c = 0; c < 8; ++c) {
      float v0 = inb ? hin[gof + ((2 * c) << 16)] : 0.0f;
      float v1 = inb ? hin[gof + ((2 * c + 1) << 16)] : 0.0f;
      pk[c] = (unsigned int)f2bf(v0) | ((unsigned int)f2bf(v1) << 16);
    }
    *(uint4*)(smem + TILE0 + i * 16) = make_uint4(pk[0], pk[1], pk[2], pk[3]);
    *(uint4*)(smem + TILE1 + i * 16) = make_uint4(pk[4], pk[5], pk[6], pk[7]);
  }
  __syncthreads();

  const int pix     = lane & 15;
  const int g       = lane >> 4;
  const int g1b     = g >> 1;                        // tap-select bit
  const int halfoff = (g & 1) ? TILE1 : TILE0;       // ci half

  const f32x4 z4 = {0.0f, 0.0f, 0.0f, 0.0f};

#pragma unroll 1
  for (int j = 0; j < 8; ++j) {
    const int bufoff = (j & 1) << 13;                // staging double-buffer

    // hv prefetch for this wave's phase-B pixel-block (row 2j+w)
    const int gbB = ib + ((Y0 + 2 * j + w) << 8) + X0 + pix;
    float hv[4];
#pragma unroll
    for (int r = 0; r < 4; ++r)
      hv[r] = hin[gbB + (((g << 2) + r) << 16)];

    // ---- phase A: GEMM1 for pb = 2j+0, 2j+1 on this wave's co slice ----
#pragma unroll
    for (int i = 0; i < 2; ++i) {
      const int pb = 2 * j + i;                      // row in tile
      const char* rowbase = smem + halfoff + (pb * 18 + pix) * 16;

      f32x4 acc[4];
#pragma unroll
      for (int ml = 0; ml < 4; ++ml) acc[ml] = z4;

#pragma unroll
      for (int kc = 0; kc < 5; ++kc) {
        const int t0   = 2 * kc;
        const int t1   = (2 * kc + 1 > 8) ? 8 : 2 * kc + 1;  // tap 9 zero-pad
        const int off0 = ((t0 / 3) * 18 + (t0 % 3)) * 16;    // compile-time
        const int off1 = ((t1 / 3) * 18 + (t1 % 3)) * 16;
        const bf16x8 b1 = *(const bf16x8*)(rowbase + (g1b ? off1 : off0));
#pragma unroll
        for (int ml = 0; ml < 4; ++ml)
          acc[ml] = __builtin_amdgcn_mfma_f32_16x16x32_bf16(a1[ml][kc], b1,
                                                            acc[ml], 0, 0, 0);
      }

      // stage relu(p) as B-fragments for kc2 = 2w+q (round-2 packing, exact)
#pragma unroll
      for (int q = 0; q < 2; ++q) {
        const int me = 2 * q, mo = 2 * q + 1;
        union { unsigned int u[4]; bf16x8 v; } bb;
        bb.u[0] = cvtpk_bf16(fmaxf(acc[me][0], 0.0f), fmaxf(acc[me][1], 0.0f));
        bb.u[1] = cvtpk_bf16(fmaxf(acc[me][2], 0.0f), fmaxf(acc[me][3], 0.0f));
        bb.u[2] = cvtpk_bf16(fmaxf(acc[mo][0], 0.0f), fmaxf(acc[mo][1], 0.0f));
        bb.u[3] = cvtpk_bf16(fmaxf(acc[mo][2], 0.0f), fmaxf(acc[mo][3], 0.0f));
        *(bf16x8*)(smem + bufoff + (i << 12) + (((w << 1) + q) << 10) +
                   (lane << 4)) = bb.v;
      }
    }
    __syncthreads();

    // ---- phase B: GEMM2 + epilogue for pb = 2j+w ----
    f32x4 dxa = z4;
    const char* bs = smem + bufoff + (w << 12) + (lane << 4);
#pragma unroll
    for (int kc2 = 0; kc2 < 4; ++kc2) {
      const bf16x8 b2 = *(const bf16x8*)(bs + (kc2 << 10));
      dxa = __builtin_amdgcn_mfma_f32_16x16x32_bf16(w2f[kc2], b2, dxa, 0, 0, 0);
    }
#pragma unroll
    for (int r = 0; r < 4; ++r) {
      const int co2 = (g << 2) + r;
      float v = hv[r] + dxa[r];
      const float lo = (co2 == 0) ? 0.0f : -3.0f;
      const float hi = (co2 == 0) ? 1.0f : 3.0f;
      v = fminf(fmaxf(v, lo), hi);
      hout[gbB + (co2 << 16)] = v;
    }
    // no trailing sync: next phase A writes buf^1; B(j) reads drain at the
    // pre-barrier lgkmcnt of sync(j+1) before A(j+2) can touch this buffer.
  }
}

// ---------------------------------------------------------------------------
extern "C" void kernel_launch(void* const* d_in, const int* in_sizes, int n_in,
                              void* d_out, int out_size, void* d_ws, size_t ws_size,
                              hipStream_t stream) {
  const float* x  = (const float*)d_in[0];
  const float* w1 = (const float*)d_in[1];
  const float* w2 = (const float*)d_in[2];
  float* out  = (float*)d_out;
  float* ping = (float*)d_ws;                                  // 33.5 MB state
  __hip_bfloat16* fr = (__hip_bfloat16*)((char*)d_ws + 33554432);

  ca_prep<<<88, 256, 0, stream>>>(w1, w2, fr);

  for (int s = 0; s < NSTEPS; ++s) {
    const float* in = (s == 0) ? x : ((s & 1) ? ping : out);
    float* o        = (s & 1) ? out : ping;                    // s=63 -> d_out
    ca_step<<<2048, 128, 0, stream>>>(in, o, fr);
  }
}

// Round 6
// 1945.624 us; speedup vs baseline: 1.7495x; 1.7495x over previous
//
#include <hip/hip_runtime.h>
#include <hip/hip_bf16.h>

#define NSTEPS 64

typedef __attribute__((ext_vector_type(8))) short bf16x8;
typedef __attribute__((ext_vector_type(4))) float f32x4;

static __device__ __forceinline__ unsigned short f2bf(float v) {
  union { __hip_bfloat16 h; unsigned short u; } cv;
  cv.h = __float2bfloat16(v);
  return cv.u;
}

static __device__ __forceinline__ unsigned int cvtpk_bf16(float lo, float hi) {
  unsigned int d;
  asm("v_cvt_pk_bf16_f32 %0, %1, %2" : "=v"(d) : "v"(lo), "v"(hi));
  return d;
}

// ---------------------------------------------------------------------------
// prep (UNCHANGED, verified rounds 1/2/4/5): MFMA A-fragments for W1/W2.
// A1 frags: [mb=8][kc=5][lane=64][j=8] bf16, PERMUTED co:
//   co(mb, m) = (mb>>1)*32 + (m>>2)*8 + (mb&1)*4 + (m&3),  m = lane&15,
//   k = 32*kc + 8*(lane>>4) + j,  k = tap*16 + ci, zero for k>=144.
// GEMM1 acc of mb pair {2q,2q+1} IS the lane-exact GEMM2 B-fragment kc2=mb>>1.
// W2 frags at element 20480: [kc2=4][lane=64][j=8], natural k2 order.
// ---------------------------------------------------------------------------
__global__ void ca_prep(const float* __restrict__ w1, const float* __restrict__ w2,
                        __hip_bfloat16* __restrict__ fr) {
  int i = blockIdx.x * 256 + threadIdx.x;
  if (i < 20480) {
    int j  = i & 7;
    int l  = (i >> 3) & 63;
    int fi = i >> 9;          // mb*5 + kc
    int kc = fi % 5, mb = fi / 5;
    int m  = l & 15;
    int co = ((mb >> 1) << 5) + ((m >> 2) << 3) + ((mb & 1) << 2) + (m & 3);
    int k  = kc * 32 + ((l >> 4) << 3) + j;
    float v = 0.0f;
    if (k < 144) {
      int tap = k >> 4, ci = k & 15;
      v = w1[(co * 16 + ci) * 9 + tap];   // w1[co][ci][dy][dx], tap=dy*3+dx
    }
    fr[i] = __float2bfloat16(v);
  } else if (i < 22528) {
    int i2  = i - 20480;
    int j   = i2 & 7;
    int l   = (i2 >> 3) & 63;
    int kc2 = i2 >> 9;
    int k2  = kc2 * 32 + ((l >> 4) << 3) + j;
    fr[i] = __float2bfloat16(w2[(l & 15) * 128 + k2]);
  }
}

// ---------------------------------------------------------------------------
// one CA step.  Intermediate state layout: NHWC f32 — one 64 B record per
// pixel, element offset = (b<<20) + (y<<12) + (x<<4) + c.  Only step 0 reads
// NCHW (input x), only step 63 writes NCHW (d_out).  Middle steps get fully
// coalesced dwordx4 tile loads, hv reads, and stores.
//
// grid = 2048: b = bid&7 (batch->XCD, per-XCD slice 4.2 MB ~ fits 4 MB L2),
// 16x16 grid of 16x16-px tiles.  block = 128 threads = 2 waves.
// Wave w owns co slice mb {4w..4w+3}; A1 frags read from global L2 ONCE per
// j (kc-outer, row-inner), W2 resident.  relu(p) exchanged as ready-made
// B-fragments via LDS (round-5-verified), double-buffered, 1 barrier per j.
//
// LDS (26752 B, 5 blocks/CU):
//   [    0, 16384)  relu(p) staging [buf=2][pb&1][kc2=4][lane=64]x16B
//   [16384, 21568)  h tile ci 0..7,  [y=18][x=18] x 16B/pixel
//   [21568, 26752)  h tile ci 8..15, same
// ---------------------------------------------------------------------------
#define TILE0 16384
#define TILE1 21568

template <bool IN_NCHW, bool OUT_NCHW>
__launch_bounds__(128, 3)
__global__ void ca_step(const float* __restrict__ hin,
                        float* __restrict__ hout,
                        const __hip_bfloat16* __restrict__ fr) {
  __shared__ __align__(16) char smem[26752];
  const int tid  = threadIdx.x;
  const int lane = tid & 63;
  const int w    = tid >> 6;          // 0..1
  const int bid  = blockIdx.x;
  const int b    = bid & 7;           // batch -> XCD round-robin
  const int t    = bid >> 3;          // 0..255
  const int ty   = t >> 4;            // 0..15
  const int tx   = t & 15;            // 0..15
  const int Y0   = ty << 4, X0 = tx << 4;
  const int ib   = b << 20;           // per-batch elements: 2^20 in BOTH layouts

  // ---- W2 resident (16 VGPR) ----
  bf16x8 w2f[4];
#pragma unroll
  for (int kc = 0; kc < 4; ++kc)
    w2f[kc] = *(const bf16x8*)(fr + 20480 + ((kc * 64 + lane) << 3));
#pragma unroll
  for (int kc = 0; kc < 4; ++kc)
    asm volatile("" : "+v"(w2f[kc]));

  // ---- halo'd tile load: 18x18 px x 16 ch, f32 -> bf16 ----
  for (int i = tid; i < 18 * 18; i += 128) {
    int y  = i / 18;
    int x  = i - y * 18;
    int GY = Y0 + y - 1, GX = X0 + x - 1;
    bool inb = ((unsigned)GY < 256u) && ((unsigned)GX < 256u);
    unsigned int pk[8];
    if (IN_NCHW) {
      int gof = ib + (GY << 8) + GX;
#pragma unroll
      for (int c = 0; c < 8; ++c) {
        float v0 = inb ? hin[gof + ((2 * c) << 16)] : 0.0f;
        float v1 = inb ? hin[gof + ((2 * c + 1) << 16)] : 0.0f;
        pk[c] = (unsigned int)f2bf(v0) | ((unsigned int)f2bf(v1) << 16);
      }
    } else {
      // NHWC: one 64 B record, 4x dwordx4, fully coalesced
      f32x4 q[4];
      if (inb) {
        const f32x4* rp = (const f32x4*)(hin + ib + (GY << 12) + (GX << 4));
#pragma unroll
        for (int qq = 0; qq < 4; ++qq) q[qq] = rp[qq];
      } else {
        const f32x4 z = {0.0f, 0.0f, 0.0f, 0.0f};
#pragma unroll
        for (int qq = 0; qq < 4; ++qq) q[qq] = z;
      }
#pragma unroll
      for (int c = 0; c < 8; ++c)
        pk[c] = (unsigned int)f2bf(q[c >> 1][(c & 1) * 2]) |
                ((unsigned int)f2bf(q[c >> 1][(c & 1) * 2 + 1]) << 16);
    }
    *(uint4*)(smem + TILE0 + i * 16) = make_uint4(pk[0], pk[1], pk[2], pk[3]);
    *(uint4*)(smem + TILE1 + i * 16) = make_uint4(pk[4], pk[5], pk[6], pk[7]);
  }
  __syncthreads();

  const int pix     = lane & 15;
  const int g       = lane >> 4;
  const int g1b     = g >> 1;                        // tap-select bit
  const int halfoff = (g & 1) ? TILE1 : TILE0;       // ci half

  const f32x4 z4 = {0.0f, 0.0f, 0.0f, 0.0f};

#pragma unroll 1
  for (int j = 0; j < 8; ++j) {
    const int bufoff = (j & 1) << 13;                // staging double-buffer

    // hv prefetch for this wave's phase-B pixel-block (row 2j+w)
    const int py = Y0 + 2 * j + w;
    float hv[4];
    int gbB_nchw = 0, gbB_nhwc = 0;
    if (IN_NCHW) {
      gbB_nchw = ib + (py << 8) + X0 + pix;
#pragma unroll
      for (int r = 0; r < 4; ++r)
        hv[r] = hin[gbB_nchw + (((g << 2) + r) << 16)];
    } else {
      gbB_nhwc = ib + (py << 12) + ((X0 + pix) << 4) + (g << 2);
      const f32x4 hvv = *(const f32x4*)(hin + gbB_nhwc);
#pragma unroll
      for (int r = 0; r < 4; ++r) hv[r] = hvv[r];
    }

    // ---- phase A: GEMM1 for rows 2j+0, 2j+1 on this wave's co slice.
    //      kc-outer: each A1 fragment fetched ONCE per j (global, L2-hot).
    f32x4 acc[2][4];
#pragma unroll
    for (int i = 0; i < 2; ++i)
#pragma unroll
      for (int ml = 0; ml < 4; ++ml) acc[i][ml] = z4;

#pragma unroll
    for (int kc = 0; kc < 5; ++kc) {
      bf16x8 a1c[4];
#pragma unroll
      for (int ml = 0; ml < 4; ++ml) {
        const int mb = (w << 2) + ml;
        a1c[ml] = *(const bf16x8*)(fr + (((mb * 5 + kc) * 64 + lane) << 3));
      }
      const int t0   = 2 * kc;
      const int t1   = (2 * kc + 1 > 8) ? 8 : 2 * kc + 1;  // tap 9 zero-pad
      const int off0 = ((t0 / 3) * 18 + (t0 % 3)) * 16;    // compile-time
      const int off1 = ((t1 / 3) * 18 + (t1 % 3)) * 16;
#pragma unroll
      for (int i = 0; i < 2; ++i) {
        const char* rowbase = smem + halfoff + ((2 * j + i) * 18 + pix) * 16;
        const bf16x8 b1 = *(const bf16x8*)(rowbase + (g1b ? off1 : off0));
#pragma unroll
        for (int ml = 0; ml < 4; ++ml)
          acc[i][ml] = __builtin_amdgcn_mfma_f32_16x16x32_bf16(a1c[ml], b1,
                                                               acc[i][ml], 0, 0, 0);
      }
    }

    // stage relu(p) as B-fragments for kc2 = 2w+q (verified packing)
#pragma unroll
    for (int i = 0; i < 2; ++i) {
#pragma unroll
      for (int q = 0; q < 2; ++q) {
        const int me = 2 * q, mo = 2 * q + 1;
        union { unsigned int u[4]; bf16x8 v; } bb;
        bb.u[0] = cvtpk_bf16(fmaxf(acc[i][me][0], 0.0f), fmaxf(acc[i][me][1], 0.0f));
        bb.u[1] = cvtpk_bf16(fmaxf(acc[i][me][2], 0.0f), fmaxf(acc[i][me][3], 0.0f));
        bb.u[2] = cvtpk_bf16(fmaxf(acc[i][mo][0], 0.0f), fmaxf(acc[i][mo][1], 0.0f));
        bb.u[3] = cvtpk_bf16(fmaxf(acc[i][mo][2], 0.0f), fmaxf(acc[i][mo][3], 0.0f));
        *(bf16x8*)(smem + bufoff + (i << 12) + (((w << 1) + q) << 10) +
                   (lane << 4)) = bb.v;
      }
    }
    __syncthreads();

    // ---- phase B: GEMM2 + epilogue for row 2j+w ----
    f32x4 dxa = z4;
    const char* bs = smem + bufoff + (w << 12) + (lane << 4);
#pragma unroll
    for (int kc2 = 0; kc2 < 4; ++kc2) {
      const bf16x8 b2 = *(const bf16x8*)(bs + (kc2 << 10));
      dxa = __builtin_amdgcn_mfma_f32_16x16x32_bf16(w2f[kc2], b2, dxa, 0, 0, 0);
    }

    if (OUT_NCHW) {
      const int gbo = ib + (py << 8) + X0 + pix;
#pragma unroll
      for (int r = 0; r < 4; ++r) {
        const int co2 = (g << 2) + r;
        float v = hv[r] + dxa[r];
        const float lo = (co2 == 0) ? 0.0f : -3.0f;
        const float hi = (co2 == 0) ? 1.0f : 3.0f;
        v = fminf(fmaxf(v, lo), hi);
        hout[gbo + (co2 << 16)] = v;
      }
    } else {
      const int gbo = ib + (py << 12) + ((X0 + pix) << 4) + (g << 2);
      f32x4 ov;
#pragma unroll
      for (int r = 0; r < 4; ++r) {
        const int co2 = (g << 2) + r;
        float v = hv[r] + dxa[r];
        const float lo = (co2 == 0) ? 0.0f : -3.0f;
        const float hi = (co2 == 0) ? 1.0f : 3.0f;
        ov[r] = fminf(fmaxf(v, lo), hi);
      }
      *(f32x4*)(hout + gbo) = ov;
    }
    // no trailing sync: next phase A writes buf^1; B(j) reads drain before
    // the barrier of j+1, so A(j+2) can't overwrite them early.
  }
}

// ---------------------------------------------------------------------------
extern "C" void kernel_launch(void* const* d_in, const int* in_sizes, int n_in,
                              void* d_out, int out_size, void* d_ws, size_t ws_size,
                              hipStream_t stream) {
  const float* x  = (const float*)d_in[0];
  const float* w1 = (const float*)d_in[1];
  const float* w2 = (const float*)d_in[2];
  float* out  = (float*)d_out;                  // NHWC scratch mid-run; NCHW at s=63
  float* ping = (float*)d_ws;                   // 33.5 MB NHWC state
  __hip_bfloat16* fr = (__hip_bfloat16*)((char*)d_ws + 33554432);

  ca_prep<<<88, 256, 0, stream>>>(w1, w2, fr);

  for (int s = 0; s < NSTEPS; ++s) {
    const float* in = (s == 0) ? x : ((s & 1) ? ping : out);
    float* o        = (s & 1) ? out : ping;     // s=63 (odd) -> d_out
    if (s == 0)
      ca_step<true, false><<<2048, 128, 0, stream>>>(in, o, fr);
    else if (s == NSTEPS - 1)
      ca_step<false, true><<<2048, 128, 0, stream>>>(in, o, fr);
    else
      ca_step<false, false><<<2048, 128, 0, stream>>>(in, o, fr);
  }
}